// Round 1
// 398.407 us; speedup vs baseline: 1.0821x; 1.0821x over previous
//
#include <hip/hip_runtime.h>

typedef __attribute__((ext_vector_type(8))) short short8;
typedef __attribute__((ext_vector_type(4))) float f32x4;
typedef unsigned short u16;
typedef unsigned int u32;

#define FENCE() asm volatile("" ::: "memory")

__device__ __forceinline__ void gld_lds16(const void* g, void* l) {
  __builtin_amdgcn_global_load_lds((const __attribute__((address_space(1))) void*)g,
                                   (__attribute__((address_space(3))) void*)l,
                                   16, 0, 0);
}

__device__ __forceinline__ u16 f2b(float x) {
  union { float f; u32 u; } v; v.f = x;
  u32 u = v.u;
  return (u16)((u + 0x7FFFu + ((u >> 16) & 1u)) >> 16);
}
__device__ __forceinline__ float b2f(u16 x) {
  union { u32 u; float f; } v; v.u = ((u32)x) << 16; return v.f;
}
__device__ __forceinline__ u32 pack_pair(float lo, float hi) {
  return (u32)f2b(lo) | ((u32)f2b(hi) << 16);
}

// ---- prep: WdT[kk][ci][co], Wup[kk][co][ci], WgS[j][co]=Wg^T*s1 (bf16); c0/tWg (fp32) ----
__global__ __launch_bounds__(256) void k_prep(const float* __restrict__ Wd, const float* __restrict__ Wg,
                                              const float* __restrict__ Wu,
                                              const float* __restrict__ s1, const float* __restrict__ t1,
                                              const float* __restrict__ bg,
                                              u16* __restrict__ WdT, u16* __restrict__ Wup,
                                              u16* __restrict__ WgS,
                                              float* __restrict__ c0, float* __restrict__ tWg) {
  int blk = blockIdx.x;
  int tid = threadIdx.x;
  if (blk == 1024) {  // c0[j] = t1 @ Wg[:,j] + bg[j]
    int j = tid;
    float a = 0.f;
    for (int co = 0; co < 256; ++co) a += t1[co] * Wg[co * 256 + j];
    tWg[j] = a;
    c0[j] = a + bg[j];
    return;
  }
  int id = blk * 256 + tid;
  if (id < 196608) {
    int kk = id >> 16;
    int rem = id & 65535;
    int a = rem >> 8, b = rem & 255;
    Wup[id] = f2b(Wu[(u32)a * 768 + (u32)b * 3 + kk]);   // Wup[kk][co=a][ci=b]
    WdT[id] = f2b(Wd[(u32)b * 768 + (u32)a * 3 + kk]);   // WdT[kk][ci=a][co=b]
  } else {
    int id2 = id - 196608;
    int j = id2 >> 8, co = id2 & 255;
    WgS[id2] = f2b(Wg[co * 256 + j] * s1[co]);
  }
}

// ---- zero the pad frames of xTz and outz (129-frame stride, 5 zero frames each) ----
__global__ __launch_bounds__(256) void k_zero(u16* __restrict__ outz, u16* __restrict__ xTz) {
  int gid = blockIdx.x * 256 + threadIdx.x;   // grid 320
  int i = gid * 8;
  int buf = (i >= 327680) ? 1 : 0;
  int wi = i - buf * 327680;
  int f = wi >> 16;          // 0..4
  int off = wi & 65535;
  u16* dst = (buf ? xTz : outz) + (size_t)f * 129 * 65536 + off;
  *(uint4*)dst = make_uint4(0u, 0u, 0u, 0u);
}

// ---- transpose+cast x[tl][ci][p] (fp32) -> xTz[pad frame][p][ci] (bf16) ----
__global__ __launch_bounds__(256) void k_transpose(const float* __restrict__ x, u16* __restrict__ xTz) {
  __shared__ u16 tile[64][72];
  int blk = blockIdx.x;
  int tl = blk >> 4;
  int sub = blk & 15;
  int ci0 = (sub >> 2) << 6;
  int p0 = (sub & 3) << 6;
  int tid = threadIdx.x;
  int i = tid >> 2;
  int ch = tid & 3;
  const float* gsrc = x + (size_t)tl * 65536 + (ci0 + i) * 256 + p0 + ch * 16;
  __align__(16) u16 cv[16];
#pragma unroll
  for (int v4 = 0; v4 < 4; ++v4) {
    float4 f = *(const float4*)(gsrc + v4 * 4);
    cv[v4 * 4 + 0] = f2b(f.x);
    cv[v4 * 4 + 1] = f2b(f.y);
    cv[v4 * 4 + 2] = f2b(f.z);
    cv[v4 * 4 + 3] = f2b(f.w);
  }
  *(uint4*)&tile[i][ch * 16] = *(const uint4*)&cv[0];
  *(uint4*)&tile[i][ch * 16 + 8] = *(const uint4*)&cv[8];
  __syncthreads();
  __align__(16) u16 tmp[16];
#pragma unroll
  for (int cc = 0; cc < 16; ++cc) tmp[cc] = tile[ch * 16 + cc][i];
  int fi = (tl >> 7) * 129 + (tl & 127) + 1;
  u16* gdst = xTz + (size_t)fi * 65536 + (p0 + i) * 256 + ci0 + ch * 16;
  *(uint4*)(gdst) = *(const uint4*)&tmp[0];
  *(uint4*)(gdst + 8) = *(const uint4*)&tmp[8];
}

// ---------------- 128-tile building blocks (k_wcomb only) ----------------
__device__ __forceinline__ void stage_tile(const u16* __restrict__ g, int ldg, u16* s, int w, int lane) {
  int r = lane >> 2;
  int cc = (lane & 3) * 8;
#pragma unroll
  for (int j = 0; j < 2; ++j) {
    gld_lds16(g + (w * 32 + j * 16 + r) * ldg + cc, s + (w * 32 + j * 16) * 32);
  }
}

__device__ __forceinline__ void mfma_tiles(const u16* sA, const u16* sB, f32x4 acc[4][4],
                                           int wr, int wc, int lane) {
  int m16 = lane & 15;
  int q8 = (lane >> 4) * 8;
  short8 a[4], b[4];
#pragma unroll
  for (int mi = 0; mi < 4; ++mi) a[mi] = *(const short8*)(sA + (wr * 64 + mi * 16 + m16) * 32 + q8);
#pragma unroll
  for (int ni = 0; ni < 4; ++ni) b[ni] = *(const short8*)(sB + (wc * 64 + ni * 16 + m16) * 32 + q8);
#pragma unroll
  for (int mi = 0; mi < 4; ++mi)
#pragma unroll
    for (int ni = 0; ni < 4; ++ni)
      acc[mi][ni] = __builtin_amdgcn_mfma_f32_16x16x32_bf16(a[mi], b[ni], acc[mi][ni], 0, 0, 0);
}

__device__ __forceinline__ void store_pairs(u16* base, int row0, int stride, int colb,
                                            const float v[4], bool ev) {
  float pv[4];
#pragma unroll
  for (int r = 0; r < 4; ++r) pv[r] = __shfl_xor(v[r], 1, 64);
  u32 wd0 = ev ? pack_pair(v[0], pv[0]) : pack_pair(pv[0], v[0]);
  u32 wd1 = ev ? pack_pair(v[1], pv[1]) : pack_pair(pv[1], v[1]);
  u32 wd2 = ev ? pack_pair(v[2], pv[2]) : pack_pair(pv[2], v[2]);
  u32 wd3 = ev ? pack_pair(v[3], pv[3]) : pack_pair(pv[3], v[3]);
  u32 wa = ev ? wd0 : wd2;
  u32 wb = ev ? wd1 : wd3;
  int rs = ev ? 0 : 2;
  *(u32*)(base + (size_t)(row0 + rs) * stride + colb) = wa;
  *(u32*)(base + (size_t)(row0 + rs + 1) * stride + colb) = wb;
}

__device__ __forceinline__ void store_pairs_f32(float* base, int row0, int stride, int colb,
                                                const float v[4], bool ev) {
  float pv[4];
#pragma unroll
  for (int r = 0; r < 4; ++r) pv[r] = __shfl_xor(v[r], 1, 64);
  float2 wa, wb;
  if (ev) { wa = make_float2(v[0], pv[0]); wb = make_float2(v[1], pv[1]); }
  else    { wa = make_float2(pv[2], v[2]); wb = make_float2(pv[3], v[3]); }
  int rs = ev ? 0 : 2;
  *(float2*)(base + (size_t)(row0 + rs) * stride + colb) = wa;
  *(float2*)(base + (size_t)(row0 + rs + 1) * stride + colb) = wb;
}

// ---- wcomb: Wcomb[kk][j][ci] = sum_co WgS[j][co] * WdT[kk][ci][co]  (12 blocks) ----
__global__ __launch_bounds__(256) void k_wcomb(const u16* __restrict__ WgS, const u16* __restrict__ WdT,
                                               u16* __restrict__ Wcomb) {
  __shared__ u16 sA[128 * 32];
  __shared__ u16 sB[128 * 32];
  int blk = blockIdx.x;
  int kk = blk >> 2;
  int tile = blk & 3;
  int tm = tile >> 1, tn = tile & 1;
  int tid = threadIdx.x, lane = tid & 63, w = tid >> 6;
  int wr = w >> 1, wc = w & 1;
  f32x4 acc[4][4];
#pragma unroll
  for (int i = 0; i < 4; ++i)
#pragma unroll
    for (int j = 0; j < 4; ++j) acc[i][j] = (f32x4){0.f, 0.f, 0.f, 0.f};
  const u16* gA = WgS + (size_t)(tm * 128) * 256;
  const u16* gB = WdT + (size_t)kk * 65536 + (size_t)(tn * 128) * 256;
  for (int ks = 0; ks < 8; ++ks) {
    stage_tile(gA + ks * 32, 256, sA, w, lane);
    stage_tile(gB + ks * 32, 256, sB, w, lane);
    __syncthreads();
    mfma_tiles(sA, sB, acc, wr, wc, lane);
    __syncthreads();
  }
  int q = lane >> 4, c = lane & 15;
  bool ev = (lane & 1) == 0;
  u16* obase = Wcomb + (size_t)kk * 65536;
#pragma unroll
  for (int mi = 0; mi < 4; ++mi) {
    int row0 = tm * 128 + wr * 64 + mi * 16 + q * 4;
#pragma unroll
    for (int ni = 0; ni < 4; ++ni) {
      float v[4];
#pragma unroll
      for (int r = 0; r < 4; ++r) v[r] = acc[mi][ni][r];
      int colb = tn * 128 + wc * 64 + ni * 16 + (c & ~1);
      store_pairs(obase, row0, 256, colb, v, ev);
    }
  }
}

// ================= 256x256 8-phase GEMM core (T1+T2+T3+T4+T5) =================
// C[256x256] = sum over 12 K-tiles (BK=64) of A[256xK] * B[256xK]^T
// A, B: row-major [row][k-contig], kk-stride 65536 elems, chunk stride 64.
// LDS: [dbuf 2][half 2][128 rows][64 k] bf16, XOR-swizzled (byte ^= (row&7)<<4),
// achieved by pre-swizzling the GLOBAL source address (LDS dest stays linear).

__device__ __forceinline__ void stage_part(int s, const u16* Ab, const u16* Bb,
                                           u16* sA, u16* sB, int wuni, int g0) {
  if (s >= 48) return;
  const int tau = s >> 2;
  const int pt = s & 3;              // 0=B0,1=B1,2=A0,3=A1
  const int toff = ((tau >> 2) << 16) + ((tau & 3) << 6);
  const int half = pt & 1;
  const u16* src = ((pt & 2) ? Ab : Bb) + toff + (half << 15) + g0;
  u16* dst = ((pt & 2) ? sA : sB) + ((tau & 1) << 14) + (half << 13) + wuni;
  gld_lds16(src, dst);
  gld_lds16(src + 16384, dst + 4096);
}

template<int QUAD, int NH>
__device__ __forceinline__ void mfma_quad(f32x4 (&acc)[8][4], const short8 (&af)[2][4],
                                          const short8 (&bf)[2][2][2]) {
#pragma unroll
  for (int k = 0; k < 2; ++k)
#pragma unroll
    for (int m = 0; m < 4; ++m)
#pragma unroll
      for (int nj = 0; nj < 2; ++nj)
        acc[QUAD * 4 + m][NH * 2 + nj] = __builtin_amdgcn_mfma_f32_16x16x32_bf16(
            af[k][m], bf[NH][k][nj], acc[QUAD * 4 + m][NH * 2 + nj], 0, 0, 0);
}

__device__ __forceinline__ void gemm256_core(const u16* __restrict__ Ab, const u16* __restrict__ Bb,
                                             u16* sA, u16* sB, int tid, f32x4 (&acc)[8][4]) {
  const int lane = tid & 63;
  const int w = tid >> 6;
  const int wr = w >> 2;        // 0..1
  const int wc = w & 3;         // 0..3
  const int m16 = lane & 15;
  const int xorm = (lane & 7) << 4;       // swizzle mask (bytes)
  const int q16b = (lane >> 4) << 4;      // k-quarter byte offset
  const int koffe0 = ((q16b) ^ xorm) >> 1;        // elems
  const int koffe1 = ((64 + q16b) ^ xorm) >> 1;   // elems
  // staging: thread's global offset (pre-swizzled so linear LDS holds swizzled data)
  const int srow = tid >> 3;                       // 0..63 (j=0)
  const int scol = ((tid & 7) ^ (srow & 7)) << 3;  // 0..56
  const int g0 = srow * 256 + scol;                // j=1 adds 16384
  const int wuni = w << 9;                         // wave-uniform LDS elem base

#pragma unroll
  for (int i = 0; i < 8; ++i)
#pragma unroll
    for (int j = 0; j < 4; ++j) acc[i][j] = (f32x4){0.f, 0.f, 0.f, 0.f};

  // prologue: stage stream parts 0..6 (tile0 all, tile1 B0,B1,A0)
#pragma unroll
  for (int s = 0; s < 7; ++s) stage_part(s, Ab, Bb, sA, sB, wuni, g0);
  asm volatile("s_waitcnt vmcnt(6)" ::: "memory");
  __builtin_amdgcn_s_barrier();
  FENCE();

  short8 af[2][4];
  short8 bf[2][2][2];
#pragma unroll 2
  for (int kt = 0; kt < 12; ++kt) {
    const int cb = kt & 1;
    const u16* aH = sA + cb * 16384 + wr * 8192;
    const u16* bH = sB + cb * 16384 + (wc >> 1) * 8192;
    const int bR0 = (wc & 1) << 6;
    // ---- phase 0: load A-quad0 + all B frags; stage A1(kt+1); MFMA Q(0,0) ----
#pragma unroll
    for (int m = 0; m < 4; ++m) {
      const u16* p = aH + (m * 16 + m16) * 64;
      af[0][m] = *(const short8*)(p + koffe0);
      af[1][m] = *(const short8*)(p + koffe1);
    }
#pragma unroll
    for (int nh = 0; nh < 2; ++nh)
#pragma unroll
      for (int nj = 0; nj < 2; ++nj) {
        const u16* p = bH + (bR0 + (nh * 2 + nj) * 16 + m16) * 64;
        bf[nh][0][nj] = *(const short8*)(p + koffe0);
        bf[nh][1][nj] = *(const short8*)(p + koffe1);
      }
    stage_part(4 * kt + 7, Ab, Bb, sA, sB, wuni, g0);
    FENCE();
    __builtin_amdgcn_s_barrier();
    FENCE();
    __builtin_amdgcn_s_setprio(1);
    mfma_quad<0, 0>(acc, af, bf);
    __builtin_amdgcn_s_setprio(0);
    FENCE();
    __builtin_amdgcn_s_barrier();
    FENCE();
    // ---- phase 1: stage B0(kt+2); MFMA Q(0,1) ----
    stage_part(4 * kt + 8, Ab, Bb, sA, sB, wuni, g0);
    FENCE();
    __builtin_amdgcn_s_barrier();
    FENCE();
    __builtin_amdgcn_s_setprio(1);
    mfma_quad<0, 1>(acc, af, bf);
    __builtin_amdgcn_s_setprio(0);
    FENCE();
    __builtin_amdgcn_s_barrier();
    FENCE();
    // ---- phase 2: reload A-quad1; stage B1(kt+2); MFMA Q(1,0) ----
#pragma unroll
    for (int m = 0; m < 4; ++m) {
      const u16* p = aH + (64 + m * 16 + m16) * 64;
      af[0][m] = *(const short8*)(p + koffe0);
      af[1][m] = *(const short8*)(p + koffe1);
    }
    stage_part(4 * kt + 9, Ab, Bb, sA, sB, wuni, g0);
    FENCE();
    __builtin_amdgcn_s_barrier();
    FENCE();
    __builtin_amdgcn_s_setprio(1);
    mfma_quad<1, 0>(acc, af, bf);
    __builtin_amdgcn_s_setprio(0);
    FENCE();
    __builtin_amdgcn_s_barrier();
    FENCE();
    // ---- phase 3: stage A0(kt+2); MFMA Q(1,1); counted vmcnt ----
    stage_part(4 * kt + 10, Ab, Bb, sA, sB, wuni, g0);
    FENCE();
    __builtin_amdgcn_s_barrier();
    FENCE();
    __builtin_amdgcn_s_setprio(1);
    mfma_quad<1, 1>(acc, af, bf);
    __builtin_amdgcn_s_setprio(0);
    if (kt < 10) asm volatile("s_waitcnt vmcnt(6)" ::: "memory");
    else         asm volatile("s_waitcnt vmcnt(0)" ::: "memory");
    __builtin_amdgcn_s_barrier();
    FENCE();
  }
}

// ---- G12: out_pre[bt][p][j] = sum_kk xTz_frames @ Wcomb_kk^T + c0 ; edge dump p<4 ----
__global__ __launch_bounds__(512, 2) void k_g12(const u16* __restrict__ xTz, const u16* __restrict__ Wcomb,
                                                const float* __restrict__ c0, const float* __restrict__ tWg,
                                                u16* __restrict__ outz, float* __restrict__ edge) {
  __shared__ u16 sA[32768];
  __shared__ u16 sB[32768];
  int bsw = (int)blockIdx.x;
  int bt = (bsw & 7) * 64 + (bsw >> 3);   // XCD swizzle (512 = 8*64)
  int b = bt >> 7, t = bt & 127;
  int tid = threadIdx.x;
  const u16* Ab = xTz + (size_t)(b * 129 + t) * 65536;
  const u16* Bb = Wcomb;
  f32x4 acc[8][4];
  gemm256_core(Ab, Bb, sA, sB, tid, acc);

  int lane = tid & 63, w = tid >> 6, wr = w >> 2, wc = w & 3;
  int q = lane >> 4, cc16 = lane & 15;
  bool ev = (lane & 1) == 0;
  float c0v[4], tWgv[4];
#pragma unroll
  for (int ni = 0; ni < 4; ++ni) {
    int j = wc * 64 + ni * 16 + cc16;
    c0v[ni] = c0[j];
    tWgv[ni] = tWg[j];
  }
  u16* obase = outz + (size_t)(b * 129 + t + 1) * 65536;
#pragma unroll
  for (int mi = 0; mi < 8; ++mi) {
    int row0 = wr * 128 + mi * 16 + q * 4;
#pragma unroll
    for (int ni = 0; ni < 4; ++ni) {
      float v[4];
#pragma unroll
      for (int r = 0; r < 4; ++r) v[r] = acc[mi][ni][r] + c0v[ni];
      store_pairs(obase, row0, 256, wc * 64 + ni * 16 + (cc16 & ~1), v, ev);
    }
  }
  if (wr == 0 && q == 0) {
    float* eb = edge + (size_t)bt * 1024;
#pragma unroll
    for (int ni = 0; ni < 4; ++ni) {
      float vE[4];
#pragma unroll
      for (int r = 0; r < 4; ++r) vE[r] = acc[0][ni][r] + tWgv[ni];
      store_pairs_f32(eb, 0, 256, wc * 64 + ni * 16 + (cc16 & ~1), vE, ev);
    }
  }
}

// ---- fixup: overwrite p<4 nodes with GCN aggregation (closed-form dinv) ----
__device__ __forceinline__ float dinv0(int t) {
  if (t == 0) return 0.44721359549995793f;   // 1/sqrt(5)
  if (t == 127) return 0.7071067811865476f;  // 1/sqrt(2)
  return 0.4082482904638631f;                // 1/sqrt(6)
}
__global__ __launch_bounds__(256) void k_fix(const float* __restrict__ edge, const float* __restrict__ bg,
                                             u16* __restrict__ outz) {
  int bt = blockIdx.x;
  int b = bt >> 7;
  int t = bt & 127;
  int j = threadIdx.x;
  const float ISQ2 = 0.7071067811865476f;
  float bgv = bg[j];
  float e_t = edge[(size_t)bt * 1024 + j];
  float At = dinv0(t);
  float o0 = bgv + At * At * e_t;
  if (t <= 126) {
    float At1 = dinv0(t + 1);
    const float* en = edge + (size_t)(bt + 1) * 1024;
    float s = At1 * en[j] + ISQ2 * (en[256 + j] + en[512 + j] + en[768 + j]);
    o0 += At * s;
  }
  float em1 = 0.f, Atm1 = 0.f;
  if (t >= 1) {
    Atm1 = dinv0(t - 1);
    em1 = edge[(size_t)(bt - 1) * 1024 + j];
    o0 += At * Atm1 * em1;
  }
  u16* ob = outz + (size_t)(b * 129 + t + 1) * 65536;
  ob[j] = f2b(o0);
#pragma unroll
  for (int k = 1; k <= 3; ++k) {
    float m = edge[(size_t)bt * 1024 + k * 256 + j];
    float ok = (t == 0) ? (bgv + m) : (bgv + 0.5f * m + ISQ2 * Atm1 * em1);
    ob[k * 256 + j] = f2b(ok);
  }
}

// ---- G3: y[bt][co][p] = (Wup_kk @ outz_frames^T)*s2 + t2, fp32 out ----
__global__ __launch_bounds__(512, 2) void k_g3(const u16* __restrict__ outz, const u16* __restrict__ Wup,
                                               const float* __restrict__ s2, const float* __restrict__ t2,
                                               float* __restrict__ y) {
  __shared__ u16 sA[32768];
  __shared__ u16 sB[32768];
  int bsw = (int)blockIdx.x;
  int bt = (bsw & 7) * 64 + (bsw >> 3);
  int b = bt >> 7, t = bt & 127;
  int tid = threadIdx.x;
  const u16* Ab = Wup;
  const u16* Bb = outz + (size_t)(b * 129 + t) * 65536;
  f32x4 acc[8][4];
  gemm256_core(Ab, Bb, sA, sB, tid, acc);

  int lane = tid & 63, w = tid >> 6, wr = w >> 2, wc = w & 3;
  int q = lane >> 4, cc16 = lane & 15;
  bool ev = (lane & 1) == 0;
  float* ybase = y + (size_t)bt * 65536;
#pragma unroll
  for (int mi = 0; mi < 8; ++mi) {
    int rl = wr * 128 + mi * 16 + q * 4;
    float4 s4 = *(const float4*)(s2 + rl);
    float4 t4 = *(const float4*)(t2 + rl);
#pragma unroll
    for (int ni = 0; ni < 4; ++ni) {
      float v[4];
      v[0] = acc[mi][ni][0] * s4.x + t4.x;
      v[1] = acc[mi][ni][1] * s4.y + t4.y;
      v[2] = acc[mi][ni][2] * s4.z + t4.z;
      v[3] = acc[mi][ni][3] * s4.w + t4.w;
      store_pairs_f32(ybase, rl, 256, wc * 64 + ni * 16 + (cc16 & ~1), v, ev);
    }
  }
}

extern "C" void kernel_launch(void* const* d_in, const int* in_sizes, int n_in,
                              void* d_out, int out_size, void* d_ws, size_t ws_size,
                              hipStream_t stream) {
  (void)in_sizes; (void)n_in; (void)out_size; (void)ws_size;
  const float* x  = (const float*)d_in[0];
  const float* Wd = (const float*)d_in[2];
  const float* s1 = (const float*)d_in[3];
  const float* t1 = (const float*)d_in[4];
  const float* Wg = (const float*)d_in[5];
  const float* bg = (const float*)d_in[6];
  const float* Wu = (const float*)d_in[7];
  const float* s2 = (const float*)d_in[8];
  const float* t2 = (const float*)d_in[9];
  float* y = (float*)d_out;
  char* ws = (char*)d_ws;
  // padded layout: 517 frames (4*129+1), frames b*129+0 / +129 are shared zero pads
  u16*   outz  = (u16*)(ws);                    // 67,764,224 B
  u16*   xTz   = (u16*)(ws + 67764224);         // 67,764,224 B
  u16*   WdT   = (u16*)(ws + 135528448);        // 384 KiB
  u16*   WgS   = (u16*)(ws + 135921664);        // 128 KiB
  u16*   Wup   = (u16*)(ws + 136052736);        // 384 KiB
  u16*   Wcomb = (u16*)(ws + 136445952);        // 384 KiB
  float* c0    = (float*)(ws + 136839168);      // 1 KiB
  float* tWg   = (float*)(ws + 136840192);      // 1 KiB
  float* edge  = (float*)d_out;                 // scratch in d_out, overwritten by k_g3

  k_prep<<<dim3(1025), dim3(256), 0, stream>>>(Wd, Wg, Wu, s1, t1, bg, WdT, Wup, WgS, c0, tWg);
  k_wcomb<<<dim3(12), dim3(256), 0, stream>>>(WgS, WdT, Wcomb);
  k_zero<<<dim3(320), dim3(256), 0, stream>>>(outz, xTz);
  k_transpose<<<dim3(8192), dim3(256), 0, stream>>>(x, xTz);
  k_g12<<<dim3(512), dim3(512), 0, stream>>>(xTz, Wcomb, c0, tWg, outz, edge);
  k_fix<<<dim3(512), dim3(256), 0, stream>>>(edge, bg, outz);
  k_g3<<<dim3(512), dim3(512), 0, stream>>>(outz, Wup, s2, t2, y);
}